// Round 17
// baseline (731.400 us; speedup 1.0000x reference)
//
#include <hip/hip_runtime.h>

#define HSZ  32
#define TLEN 1024
#define PS   40   // f16 stride per col in a plane (80 B: 16B-aligned b128 reads)

typedef _Float16 half8 __attribute__((ext_vector_type(8)));
typedef float    f32x4 __attribute__((ext_vector_type(4)));

__device__ __forceinline__ float rcp_f(float x){ return __builtin_amdgcn_rcpf(x); }
__device__ __forceinline__ float exp2_f(float x){ return __builtin_amdgcn_exp2f(x); }
#define SCL_S (-1.442695040888963f)   // sigmoid arg prescale: -log2(e)
#define SCL_T ( 2.885390081777927f)   // tanh arg prescale: +2*log2(e)

__device__ __forceinline__ f32x4 mfma16(half8 a, half8 b, f32x4 c){
  return __builtin_amdgcn_mfma_f32_16x16x32_f16(a, b, c, 0, 0, 0);
}
// LDS-only barrier: drain lgkmcnt without draining vmcnt (x prefetch in flight).
__device__ __forceinline__ void lds_barrier(){
  asm volatile("s_waitcnt lgkmcnt(0)\n\ts_barrier" ::: "memory");
}

// gate quad from prescaled args; paired rcps; updates CV in place; OV pre-declared.
#define ACT4(A0,A1,A2,A3, CV, OV)                              \
  { float Zi_ = exp2_f(A0), Zf_ = exp2_f(A1);                  \
    float Zg_ = exp2_f(A2), Zo_ = exp2_f(A3);                  \
    float di_ = 1.f+Zi_, df_ = 1.f+Zf_;                        \
    float dg_ = 1.f+Zg_, dq_ = 1.f+Zo_;                        \
    float r1_ = rcp_f(di_*df_);                                \
    float IV_ = r1_*df_, FV_ = r1_*di_;                        \
    float r2_ = rcp_f(dg_*dq_);                                \
    float GV_ = fmaf(-2.f, r2_*dq_, 1.f); OV = r2_*dg_;        \
    CV = fmaf(FV_, CV, IV_*GV_); }

// paired tanh(c) for two cell states: one rcp. HA/HB pre-declared.
#define TANHPAIR(CA, CB, OA, OB, HA, HB)                       \
  { float ZA_ = exp2_f(SCL_T*(CA)), ZB_ = exp2_f(SCL_T*(CB));  \
    float dA_ = 1.f+ZA_, dB_ = 1.f+ZB_;                        \
    float re_ = rcp_f(dA_*dB_);                                \
    float qA_ = re_*dB_*(OA), qB_ = re_*dA_*(OB);              \
    HA = fmaf(-2.f, qA_, OA); HB = fmaf(-2.f, qB_, OB); }

// DUAL HALF-TILE INTERLEAVE, 8 waves / 16-batch tile (2 waves/SIMD):
// The 16 cols split into TWO INDEPENDENT 8-col recurrences:
//   P: B-cols 0..7 valid (lanes c<8), Q: B-cols 8..15 valid (lanes c>=8),
// carried by the SAME waves with the SAME weights (A-operand is col-blind;
// MFMA is column-independent so garbage in the other half's col-lanes never
// contaminates valid cols -- it stays bounded, no NaN). Each interval runs
// one R9-style skewed step (L1(t) + L0(t+1), 6 MFMA, 2 ACT4 + TANHPAIR) for
// EACH half, writes both, takes ONE lgkm-only barrier, then reads BOTH
// halves' next-step fragments. Every ds_read is therefore issued a full
// interval before first use -> the ~120cy LDS read latency leaves the
// recurrence critical chain (what R13/R16 tried to buy with extra barriers).
// Chain per interval ~ MFMA + acts only; the two act bursts de-phase the
// trans pipe. h f16-hi only; weights hi+lo split; permuted A-rows (gate quad
// in-lane); parity double-buffered planes per half (R9's proven discipline).
__global__ __launch_bounds__(512, 2) void lstm2_dual(
    const float* __restrict__ x,
    const float* __restrict__ Wih0, const float* __restrict__ Whh0,
    const float* __restrict__ bih0, const float* __restrict__ bhh0,
    const float* __restrict__ Wih1, const float* __restrict__ Whh1,
    const float* __restrict__ bih1, const float* __restrict__ bhh1,
    const float* __restrict__ Wfc,  const float* __restrict__ bfc,
    float* __restrict__ out, int Tn)
{
  // [parity][layer][col*PS + k], one set per half
  __shared__ __align__(16) _Float16 hP[2][2][16*PS];
  __shared__ __align__(16) _Float16 hQ[2][2][16*PS];

  const int tid = threadIdx.x;
  const int w   = tid >> 6;
  const int l   = tid & 63;
  const int c   = l & 15;        // batch col == A tile-row index
  const int g   = l >> 4;        // k-group == D row-group
  const int s   = 4*w + g;       // state this lane owns
  const int b0  = blockIdx.x * 16;

  // ---- A fragments: hi+lo split, prescaled, permuted rows, k = 8g+j (shared by halves) ----
  const int prow = 32*(c & 3) + 4*w + (c >> 2);
  const float sA = ((c & 3) == 2) ? SCL_T : SCL_S;
  half8 W0h, W0l, WIh, WIl, WHh, WHl;
  {
    const float* p0 = Whh0 + prow*HSZ + 8*g;
    const float* p1 = Wih1 + prow*HSZ + 8*g;
    const float* p2 = Whh1 + prow*HSZ + 8*g;
    #pragma unroll
    for (int j = 0; j < 8; ++j){
      float v0 = p0[j]*sA, v1 = p1[j]*sA, v2 = p2[j]*sA;
      _Float16 a = (_Float16)v0; W0h[j] = a; W0l[j] = (_Float16)(v0 - (float)a);
      _Float16 b = (_Float16)v1; WIh[j] = b; WIl[j] = (_Float16)(v1 - (float)b);
      _Float16 d = (_Float16)v2; WHh[j] = d; WHl[j] = (_Float16)(v2 - (float)d);
    }
  }
  // D reg j = physical gate row 32j + s; per-gate prescale (j=2 is tanh)
  const float scj[4] = {SCL_S, SCL_S, SCL_T, SCL_S};
  float wx[4], bs0[4];
  f32x4 bias1;
  #pragma unroll
  for (int j = 0; j < 4; ++j){
    int r    = 32*j + s;
    wx[j]    = Wih0[r] * scj[j];
    bs0[j]   = (bih0[r] + bhh0[r]) * scj[j];
    bias1[j] = (bih1[r] + bhh1[r]) * scj[j];
  }
  const f32x4 zero4 = {0.f, 0.f, 0.f, 0.f};

  const int wrI = c*PS + s;       // this lane's h write slot (f16 index)
  const int rdI = c*PS + 8*g;     // b128 read base (16B aligned)

  for (int i = tid; i < 2*2*16*PS; i += 512){
    (&hP[0][0][0])[i] = (_Float16)0.0f;
    (&hQ[0][0][0])[i] = (_Float16)0.0f;
  }

  const float* xp = x + (size_t)(b0 + c) * Tn;   // lane's own col (P valid c<8, Q valid c>=8)
  float c0P = 0.f, c1P = 0.f, c0Q = 0.f, c1Q = 0.f;
  float h1P = 0.f, h1Q = 0.f;

  // ---- prologue: L0(0) per lane-col (no MFMA); same value feeds both halves ----
  {
    float x0 = xp[0];
    float a0 = fmaf(x0, wx[0], bs0[0]);
    float a1 = fmaf(x0, wx[1], bs0[1]);
    float a2 = fmaf(x0, wx[2], bs0[2]);
    float a3 = fmaf(x0, wx[3], bs0[3]);
    float c0 = 0.f, o0_;
    ACT4(a0, a1, a2, a3, c0, o0_);
    float Zc = exp2_f(SCL_T * c0);
    float rc = rcp_f(1.f + Zc);
    float h0 = fmaf(-2.f, rc * o0_, o0_);
    __syncthreads();                       // zero-init visible before overwrite
    hP[0][0][wrI] = (_Float16)h0;
    hQ[0][0][wrI] = (_Float16)h0;
    c0P = c0; c0Q = c0;
  }
  __syncthreads();
  half8 BP0 = *(const half8*)&hP[0][0][rdI];   // h0(0), P
  half8 BP1 = *(const half8*)&hP[0][1][rdI];   // h1(-1) = 0
  half8 BQ0 = *(const half8*)&hQ[0][0][rdI];   // h0(0), Q
  half8 BQ1 = *(const half8*)&hQ[0][1][rdI];
  float xv = xp[1];                             // x(1), consumed in iter 0

  // iter t: for EACH half, L1(t) -> h1(t) AND L0(t+1) -> h0(t+1); parity PQ=(t+1)&1
#define STEP(PQ, TIDX)                                                     \
  {                                                                        \
    float xn = xp[(TIDX)];              /* prefetch x(t+2), stays in flight */ \
    /* ---- Q half (cols 8..15 valid) ---- */                              \
    f32x4 eQ;                                                              \
    eQ[0] = fmaf(xv, wx[0], bs0[0]);                                       \
    eQ[1] = fmaf(xv, wx[1], bs0[1]);                                       \
    eQ[2] = fmaf(xv, wx[2], bs0[2]);                                       \
    eQ[3] = fmaf(xv, wx[3], bs0[3]);                                       \
    f32x4 uQ = mfma16(WHh, BQ1, bias1);                                    \
    f32x4 vQ = mfma16(WIh, BQ0, zero4);                                    \
    eQ = mfma16(W0h, BQ0, eQ);                                             \
    uQ = mfma16(WHl, BQ1, uQ);                                             \
    vQ = mfma16(WIl, BQ0, vQ);                                             \
    eQ = mfma16(W0l, BQ0, eQ);                                             \
    f32x4 aQ = uQ + vQ;                                                    \
    float o1Q_, o0Q_, h0Qv;                                                \
    ACT4(aQ[0],aQ[1],aQ[2],aQ[3], c1Q, o1Q_);                              \
    ACT4(eQ[0],eQ[1],eQ[2],eQ[3], c0Q, o0Q_);                              \
    TANHPAIR(c1Q, c0Q, o1Q_, o0Q_, h1Q, h0Qv);                             \
    hQ[(PQ)][1][wrI] = (_Float16)h1Q;                                      \
    hQ[(PQ)][0][wrI] = (_Float16)h0Qv;                                     \
    /* ---- P half (cols 0..7 valid) ---- */                               \
    f32x4 eP;                                                              \
    eP[0] = fmaf(xv, wx[0], bs0[0]);                                       \
    eP[1] = fmaf(xv, wx[1], bs0[1]);                                       \
    eP[2] = fmaf(xv, wx[2], bs0[2]);                                       \
    eP[3] = fmaf(xv, wx[3], bs0[3]);                                       \
    f32x4 uP = mfma16(WHh, BP1, bias1);                                    \
    f32x4 vP = mfma16(WIh, BP0, zero4);                                    \
    eP = mfma16(W0h, BP0, eP);                                             \
    uP = mfma16(WHl, BP1, uP);                                             \
    vP = mfma16(WIl, BP0, vP);                                             \
    eP = mfma16(W0l, BP0, eP);                                             \
    f32x4 aP = uP + vP;                                                    \
    float o1P_, o0P_, h0Pv;                                                \
    ACT4(aP[0],aP[1],aP[2],aP[3], c1P, o1P_);                              \
    ACT4(eP[0],eP[1],eP[2],eP[3], c0P, o0P_);                              \
    TANHPAIR(c1P, c0P, o1P_, o0P_, h1P, h0Pv);                             \
    hP[(PQ)][1][wrI] = (_Float16)h1P;                                      \
    hP[(PQ)][0][wrI] = (_Float16)h0Pv;                                     \
    lds_barrier();                                                         \
    /* reads for NEXT interval: full interval of lead time */              \
    BQ0 = *(const half8*)&hQ[(PQ)][0][rdI];                                \
    BQ1 = *(const half8*)&hQ[(PQ)][1][rdI];                                \
    BP0 = *(const half8*)&hP[(PQ)][0][rdI];                                \
    BP1 = *(const half8*)&hP[(PQ)][1][rdI];                                \
    xv = xn;                                                               \
  }

  for (int T0 = 0; T0 < Tn; T0 += 2){
    STEP(1, (T0+2 < Tn) ? T0+2 : Tn-1);
    STEP(0, (T0+3 < Tn) ? T0+3 : Tn-1);
  }
#undef STEP

  // ---- FC head: out[b0+c] = dot(h1_final[:,c], Wfc) + bfc ----
  __syncthreads();
  float* sc = (float*)&hP[0][0][0];
  sc[s*17 + c] = (c < 8) ? h1P : h1Q;
  __syncthreads();
  if (tid < 16){
    float acc = bfc[0];
    #pragma unroll 8
    for (int k = 0; k < HSZ; ++k) acc = fmaf(sc[k*17 + tid], Wfc[k], acc);
    out[b0 + tid] = acc;
  }
}

extern "C" void kernel_launch(void* const* d_in, const int* in_sizes, int n_in,
                              void* d_out, int out_size, void* d_ws, size_t ws_size,
                              hipStream_t stream) {
  const float* x    = (const float*)d_in[0];
  const float* Wih0 = (const float*)d_in[1];
  const float* Whh0 = (const float*)d_in[2];
  const float* bih0 = (const float*)d_in[3];
  const float* bhh0 = (const float*)d_in[4];
  const float* Wih1 = (const float*)d_in[5];
  const float* Whh1 = (const float*)d_in[6];
  const float* bih1 = (const float*)d_in[7];
  const float* bhh1 = (const float*)d_in[8];
  const float* Wfc  = (const float*)d_in[9];
  const float* bfc  = (const float*)d_in[10];
  float* out = (float*)d_out;

  const int Tn = TLEN;
  const int B  = in_sizes[0] / Tn;     // x is (B, T, 1)

  dim3 block(512);
  dim3 grid(B / 16);
  hipLaunchKernelGGL(lstm2_dual, grid, block, 0, stream,
                     x, Wih0, Whh0, bih0, bhh0, Wih1, Whh1, bih1, bhh1,
                     Wfc, bfc, out, Tn);
}

// Round 18
// 408.271 us; speedup vs baseline: 1.7915x; 1.7915x over previous
//
#include <hip/hip_runtime.h>

#define HSZ  32
#define TLEN 1024
#define PS   40   // f16 stride per col in a plane (80 B: 16B-aligned b128 reads)

typedef _Float16 half8 __attribute__((ext_vector_type(8)));
typedef float    f32x4 __attribute__((ext_vector_type(4)));

__device__ __forceinline__ float rcp_f(float x){ return __builtin_amdgcn_rcpf(x); }
__device__ __forceinline__ float exp2_f(float x){ return __builtin_amdgcn_exp2f(x); }
#define SCL_S (-1.442695040888963f)   // sigmoid arg prescale: -log2(e)
#define SCL_T ( 2.885390081777927f)   // tanh arg prescale: +2*log2(e)

__device__ __forceinline__ f32x4 mfma16(half8 a, half8 b, f32x4 c){
  return __builtin_amdgcn_mfma_f32_16x16x32_f16(a, b, c, 0, 0, 0);
}
// LDS-only barrier: drain lgkmcnt without draining vmcnt (x prefetch in flight).
__device__ __forceinline__ void lds_barrier(){
  asm volatile("s_waitcnt lgkmcnt(0)\n\ts_barrier" ::: "memory");
}

// gate quad from prescaled args; paired rcps; updates CV in place.
#define ACT4(A0,A1,A2,A3, CV, OV)                              \
  float OV;                                                    \
  { float Zi_ = exp2_f(A0), Zf_ = exp2_f(A1);                  \
    float Zg_ = exp2_f(A2), Zo_ = exp2_f(A3);                  \
    float di_ = 1.f+Zi_, df_ = 1.f+Zf_;                        \
    float dg_ = 1.f+Zg_, dq_ = 1.f+Zo_;                        \
    float r1_ = rcp_f(di_*df_);                                \
    float IV_ = r1_*df_, FV_ = r1_*di_;                        \
    float r2_ = rcp_f(dg_*dq_);                                \
    float GV_ = fmaf(-2.f, r2_*dq_, 1.f); OV = r2_*dg_;        \
    CV = fmaf(FV_, CV, IV_*GV_); }

// h = o * tanh(c), prescaled: tanh = 1 - 2*rcp(1+exp2(SCL_T*c))
#define HOUT(CV, OV, HV)                                       \
  { float Zc_ = exp2_f(SCL_T*(CV));                            \
    float rc_ = rcp_f(1.f + Zc_);                              \
    HV = fmaf(-2.f, rc_*(OV), OV); }

// 16 waves / 16-batch tile (4 waves/SIMD) -- session best (R14, 408.0 us).
//  waves 0-7  (L0): 1 permuted D-tile = 4 states, 2 MFMA/step.
//  waves 8-15 (L1): 1 D-tile = 4 states, 4 MFMA/step (Whh1*h1 + Wih1*h0).
// Permuted A-rows (32*(r&3)+4*tau+(r>>2)): lane (g,c) D-regs j=0..3 = gates
// (i,f,g,o) of state 4*tau+g -- quad in-lane, no gate LDS round-trip.
// h exchanged as f16-hi only; weights hi+lo split; one lgkm-only barrier/step;
// parity double-buffered planes.
__global__ __launch_bounds__(1024, 4) void lstm2_w16b(
    const float* __restrict__ x,
    const float* __restrict__ Wih0, const float* __restrict__ Whh0,
    const float* __restrict__ bih0, const float* __restrict__ bhh0,
    const float* __restrict__ Wih1, const float* __restrict__ Whh1,
    const float* __restrict__ bih1, const float* __restrict__ bhh1,
    const float* __restrict__ Wfc,  const float* __restrict__ bfc,
    float* __restrict__ out, int Tn)
{
  __shared__ __align__(16) _Float16 hpl[2][2][16*PS];  // [parity][layer][col*PS+k]

  const int tid = threadIdx.x;
  const int w   = tid >> 6;
  const int l   = tid & 63;
  const int col = l & 15;        // batch col == A tile-row index
  const int g   = l >> 4;        // k-group == D row-group
  const int b0  = blockIdx.x * 16;
  const bool isL0 = (w < 8);
  const int wl  = isL0 ? w : (w - 8);   // tile index 0..7
  const int st  = 4*wl + g;             // state this lane owns

  const int rdI = col*PS + 8*g;         // b128 read (16B-aligned)
  const int wrI = col*PS + st;          // this lane's h write
  const float sA = ((col & 3) == 2) ? SCL_T : SCL_S;
  const float scj[4] = {SCL_S, SCL_S, SCL_T, SCL_S};
  const f32x4 zero4 = {0.f, 0.f, 0.f, 0.f};
  const int prow = 32*(col & 3) + 4*wl + (col >> 2);

  for (int i = tid; i < 2*2*16*PS; i += 1024) (&hpl[0][0][0])[i] = (_Float16)0.0f;

  // ---- per-role weight/bias loads (divergent, no barrier inside) ----
  half8 WAh, WAl;                  // L0: Whh0 hi/lo | L1: Whh1 hi/lo
  half8 WIh, WIl;                  // L1 only: Wih1 hi/lo
  f32x4 bias1;                     // L1 only
  float wx[4], bs0[4];             // L0 only
  const float* xp = x + (size_t)(b0 + col) * Tn;

  if (isL0){
    const float* p0 = Whh0 + prow*HSZ + 8*g;
    #pragma unroll
    for (int j = 0; j < 8; ++j){
      float v0 = p0[j]*sA;
      _Float16 a = (_Float16)v0; WAh[j] = a; WAl[j] = (_Float16)(v0 - (float)a);
    }
    #pragma unroll
    for (int j = 0; j < 4; ++j){
      int r  = 32*j + st;
      wx[j]  = Wih0[r] * scj[j];
      bs0[j] = (bih0[r] + bhh0[r]) * scj[j];
    }
  } else {
    const float* pH = Whh1 + prow*HSZ + 8*g;
    const float* pI = Wih1 + prow*HSZ + 8*g;
    #pragma unroll
    for (int j = 0; j < 8; ++j){
      float v2 = pH[j]*sA, v1 = pI[j]*sA;
      _Float16 c = (_Float16)v2; WAh[j] = c; WAl[j] = (_Float16)(v2 - (float)c);
      _Float16 b = (_Float16)v1; WIh[j] = b; WIl[j] = (_Float16)(v1 - (float)b);
    }
    #pragma unroll
    for (int j = 0; j < 4; ++j){
      int r = 32*j + st;
      bias1[j] = (bih1[r] + bhh1[r]) * scj[j];
    }
  }

  float cSt = 0.f, hFin = 0.f;     // recurrent cell state / last h (per role)

  __syncthreads();   // [A] zero-init visible

  // ---- prologue: L0 computes h0(0) (no MFMA, h0(-1)=0); h1(-1)=0 already ----
  if (isL0){
    float x0 = xp[0];
    ACT4(fmaf(x0,wx[0],bs0[0]), fmaf(x0,wx[1],bs0[1]),
         fmaf(x0,wx[2],bs0[2]), fmaf(x0,wx[3],bs0[3]), cSt, ov0_);
    float h0;
    HOUT(cSt, ov0_, h0);
    hpl[0][0][wrI] = (_Float16)h0;
  }
  __syncthreads();   // [B] h0(0) visible

  if (isL0){
    // ================= LAYER-0 (1 tile, 2 MFMA/step) =================
    half8 Bh0 = *(const half8*)&hpl[0][0][rdI];   // h0(0)
    float xv = xp[1];

#define L0STEP(Q, XNI)                                                     \
    {                                                                      \
      float xn = xp[(XNI)];                                                \
      f32x4 e;                                                             \
      e[0]=fmaf(xv,wx[0],bs0[0]); e[1]=fmaf(xv,wx[1],bs0[1]);              \
      e[2]=fmaf(xv,wx[2],bs0[2]); e[3]=fmaf(xv,wx[3],bs0[3]);              \
      e = mfma16(WAh, Bh0, e);                                             \
      e = mfma16(WAl, Bh0, e);                                             \
      ACT4(e[0],e[1],e[2],e[3], cSt, ov_);                                 \
      float h0;                                                            \
      HOUT(cSt, ov_, h0);                                                  \
      hpl[(Q)][0][wrI] = (_Float16)h0;                                     \
      lds_barrier();                                                       \
      Bh0 = *(const half8*)&hpl[(Q)][0][rdI];                              \
      xv = xn;                                                             \
    }

    for (int T0 = 0; T0 < Tn; T0 += 2){
      L0STEP(1, (T0+2 < Tn) ? T0+2 : Tn-1);
      L0STEP(0, (T0+3 < Tn) ? T0+3 : Tn-1);
    }
#undef L0STEP
  } else {
    // ================= LAYER-1 (1 tile, 4 MFMA/step) =================
    half8 Bh0 = *(const half8*)&hpl[0][0][rdI];   // h0(0)
    half8 Bh1 = *(const half8*)&hpl[0][1][rdI];   // h1(-1) = 0

#define L1STEP(Q)                                                          \
    {                                                                      \
      f32x4 u, vv;                                                         \
      u  = mfma16(WAh, Bh1, bias1);                                        \
      vv = mfma16(WIh, Bh0, zero4);                                        \
      u  = mfma16(WAl, Bh1, u);                                            \
      vv = mfma16(WIl, Bh0, vv);                                           \
      f32x4 a = u + vv;                                                    \
      ACT4(a[0],a[1],a[2],a[3], cSt, ov_);                                 \
      HOUT(cSt, ov_, hFin);                                                \
      hpl[(Q)][1][wrI] = (_Float16)hFin;                                   \
      lds_barrier();                                                       \
      Bh0 = *(const half8*)&hpl[(Q)][0][rdI];                              \
      Bh1 = *(const half8*)&hpl[(Q)][1][rdI];                              \
    }

    for (int T0 = 0; T0 < Tn; T0 += 2){
      L1STEP(1);
      L1STEP(0);
    }
#undef L1STEP
  }

  // ---- FC head: out[b0+c] = dot(h1_final[:,c], Wfc) + bfc ----
  __syncthreads();   // [C] loops done everywhere
  float* sc = (float*)&hpl[0][0][0];
  if (!isL0){
    sc[st*17 + col] = hFin;
  }
  __syncthreads();   // [D]
  if (tid < 16){
    float acc = bfc[0];
    #pragma unroll 8
    for (int k = 0; k < HSZ; ++k) acc = fmaf(sc[k*17 + tid], Wfc[k], acc);
    out[b0 + tid] = acc;
  }
}

extern "C" void kernel_launch(void* const* d_in, const int* in_sizes, int n_in,
                              void* d_out, int out_size, void* d_ws, size_t ws_size,
                              hipStream_t stream) {
  const float* x    = (const float*)d_in[0];
  const float* Wih0 = (const float*)d_in[1];
  const float* Whh0 = (const float*)d_in[2];
  const float* bih0 = (const float*)d_in[3];
  const float* bhh0 = (const float*)d_in[4];
  const float* Wih1 = (const float*)d_in[5];
  const float* Whh1 = (const float*)d_in[6];
  const float* bih1 = (const float*)d_in[7];
  const float* bhh1 = (const float*)d_in[8];
  const float* Wfc  = (const float*)d_in[9];
  const float* bfc  = (const float*)d_in[10];
  float* out = (float*)d_out;

  const int Tn = TLEN;
  const int B  = in_sizes[0] / Tn;     // x is (B, T, 1)

  dim3 block(1024);
  dim3 grid(B / 16);
  hipLaunchKernelGGL(lstm2_w16b, grid, block, 0, stream,
                     x, Wih0, Whh0, bih0, bhh0, Wih1, Whh1, bih1, bhh1,
                     Wfc, bfc, out, Tn);
}